// Round 5
// baseline (166.469 us; speedup 1.0000x reference)
//
#include <hip/hip_runtime.h>
#include <cstdint>

typedef __attribute__((ext_vector_type(8))) short short8;
typedef __attribute__((ext_vector_type(16))) float f32x16;

__device__ inline uint32_t f2bf(float f) {
    union { float f; uint32_t u; } x; x.f = f;
    return (x.u + 0x7FFF + ((x.u >> 16) & 1)) >> 16;
}

// Convert kernel fp32 [9][64][64] -> bf16 ktb (same order), init bias outputs.
__global__ void k_prep(const float* __restrict__ kk, uint16_t* __restrict__ ktb,
                       const float* __restrict__ buI, const float* __restrict__ blI,
                       float* __restrict__ buO, float* __restrict__ blO) {
    int i = blockIdx.x * 256 + threadIdx.x;
    if (i < 36864) ktb[i] = (uint16_t)f2bf(kk[i]);
    else if (i < 36864 + 256) buO[i - 36864] = buI[i - 36864];
    else if (i < 36864 + 512) blO[i - 36864 - 256] = blI[i - 36864 - 256];
}

// Block: (b, UL, h, w-chunk of 8). 4 waves, wave owns 2 w's.
// LDS: ONE kh-row of 10 sites, site = [32 o][64 co] bf16 XOR-swizzled 16B chunks.
// 10 * 4096 = 40960 B exactly -> 4 blocks/CU.
__global__ __launch_bounds__(256, 4) void k_main(
    const float* __restrict__ wu, const float* __restrict__ wl,
    const uint16_t* __restrict__ ktb, const float* __restrict__ bias,
    float* __restrict__ outU, float* __restrict__ outL,
    float* __restrict__ buO, float* __restrict__ blO)
{
    __shared__ uint16_t tiles[10][2048];    // 40960 B exactly

    int t  = threadIdx.x;
    int l  = t & 63;
    int wv = t >> 6;
    int o  = l & 31;            // n_out index (frag col, stride-1 in memory)
    int ch = l >> 5;            // co-half selector (compute phase)

    // staging lane geometry: q = o-quad, g = co-pair index
    int q  = l & 7;             // o0 = 4q
    int g  = l >> 3;            // co = 2g + 16p
    int o0 = q * 4;

    // XCD-chunk swizzle: h innermost within an XCD's contiguous chunk
    int bid  = blockIdx.x;
    int virt = (bid & 7) * 256 + (bid >> 3);
    int h    = virt & 31;
    int wc   = (virt >> 5) & 3;
    int UL   = (virt >> 7) & 1;
    int b    = virt >> 8;
    int w0   = wc * 8;

    const float* src = UL ? wl : wu;
    float* dst  = UL ? outL : outU;
    float* bdst = UL ? blO : buO;

    // bias values for this thread's co pairs (hoisted, 8 regs)
    float2 breg[4];
    #pragma unroll
    for (int p = 0; p < 4; p++)
        breg[p] = *(const float2*)(bias + 2 * g + 16 * p);

    float bp[4] = {0.f, 0.f, 0.f, 0.f};    // bias partials for o = o0+0..3

    f32x16 acc[2][2];
    #pragma unroll
    for (int a = 0; a < 2; a++)
        #pragma unroll
        for (int c = 0; c < 2; c++) acc[a][c] = (f32x16)0.f;

    for (int r = 0; r < 3; r++) {
        int hh = h + 1 - r;                 // adjoint: row h reads conv-out row h+1-kh
        if ((unsigned)hh >= 32u) continue;  // block-uniform

        __syncthreads();                    // previous row's readers done

        // ---- stage row r: sites wv, wv+4, wv+8 ----
        for (int s = wv; s < 10; s += 4) {
            int ww = w0 - 1 + s;
            char* lp = (char*)tiles + s * 4096;
            if ((unsigned)ww >= 32u) {
                #pragma unroll
                for (int p = 0; p < 4; p++) {
                    int co    = 2 * g + 16 * p;
                    int chunk = (g >> 2) + 2 * p;
                    int cb    = (co & 7) << 1;
                    #pragma unroll
                    for (int dd = 0; dd < 4; dd++) {
                        int oo = o0 + dd;
                        *(uint32_t*)(lp + oo * 128 + ((chunk ^ (oo & 7)) << 4) + cb) = 0u;
                    }
                }
                continue;
            }
            const float* base = src + ((size_t)b * 65536 + (size_t)(hh * 32 + ww) * 64) * 32;
            // issue all 8 coalesced 16B loads before any use (deep MLP)
            float4 gA[4], gB[4];
            #pragma unroll
            for (int p = 0; p < 4; p++) {
                int co = 2 * g + 16 * p;
                gA[p] = *(const float4*)(base + co * 32 + o0);
                gB[p] = *(const float4*)(base + (co + 1) * 32 + o0);
            }
            bool ctr = (r == 1) && (s >= 1) && (s <= 8);   // center row: each elem once
            #pragma unroll
            for (int p = 0; p < 4; p++) {
                int co    = 2 * g + 16 * p;
                int chunk = (g >> 2) + 2 * p;
                int cb    = (co & 7) << 1;
                if (ctr) {
                    bp[0] = fmaf(gA[p].x, breg[p].x, fmaf(gB[p].x, breg[p].y, bp[0]));
                    bp[1] = fmaf(gA[p].y, breg[p].x, fmaf(gB[p].y, breg[p].y, bp[1]));
                    bp[2] = fmaf(gA[p].z, breg[p].x, fmaf(gB[p].z, breg[p].y, bp[2]));
                    bp[3] = fmaf(gA[p].w, breg[p].x, fmaf(gB[p].w, breg[p].y, bp[3]));
                }
                uint32_t d0 = f2bf(gA[p].x) | (f2bf(gB[p].x) << 16);
                uint32_t d1 = f2bf(gA[p].y) | (f2bf(gB[p].y) << 16);
                uint32_t d2 = f2bf(gA[p].z) | (f2bf(gB[p].z) << 16);
                uint32_t d3 = f2bf(gA[p].w) | (f2bf(gB[p].w) << 16);
                uint32_t dw[4] = {d0, d1, d2, d3};
                #pragma unroll
                for (int dd = 0; dd < 4; dd++) {
                    int oo = o0 + dd;
                    *(uint32_t*)(lp + oo * 128 + ((chunk ^ (oo & 7)) << 4) + cb) = dw[dd];
                }
            }
        }

        __syncthreads();                    // row staged

        // ---- compute row r (kidx outer: only 6 A-frags live) ----
        #pragma unroll
        for (int kidx = 0; kidx < 4; kidx++) {
            short8 A[3][2];
            #pragma unroll
            for (int kw = 0; kw < 3; kw++)
                #pragma unroll
                for (int c = 0; c < 2; c++)
                    A[kw][c] = *(const short8*)&ktb[(((r * 3 + kw) * 64) + c * 32 + (l & 31)) * 64
                                                    + kidx * 16 + ch * 8];
            #pragma unroll
            for (int si = 0; si < 4; si++) {
                int s = 2 * wv + si;
                int chunk = kidx * 2 + ch;
                short8 Bf = *(const short8*)&tiles[s][o * 64 + ((chunk ^ (o & 7)) << 3)];
                #pragma unroll
                for (int tw = 0; tw < 2; tw++) {
                    int kw = tw + 2 - si;              // compile-time under unroll
                    if (kw >= 0 && kw <= 2) {
                        #pragma unroll
                        for (int c = 0; c < 2; c++)
                            acc[tw][c] = __builtin_amdgcn_mfma_f32_32x32x16_bf16(
                                A[kw][c], Bf, acc[tw][c], 0, 0, 0);
                    }
                }
            }
        }
    }

    // ---- bias reduction: shfl pre-reduce (lanes sharing o differ in g bits) ----
    #pragma unroll
    for (int dd = 0; dd < 4; dd++) {
        float v = bp[dd];
        v += __shfl_xor(v, 8);
        v += __shfl_xor(v, 16);
        v += __shfl_xor(v, 32);
        bp[dd] = v;
    }
    __syncthreads();                       // compute done; tiles reusable
    float* bsum = (float*)&tiles[0][0];
    if (t < 32) bsum[t] = 0.f;
    __syncthreads();
    if (g == 0) {                          // lane q of each wave holds wave totals
        #pragma unroll
        for (int dd = 0; dd < 4; dd++) atomicAdd(&bsum[4 * q + dd], bp[dd]);
    }
    __syncthreads();
    if (t < 32) atomicAdd(&bdst[b * 32 + t], bsum[t]);

    // ---- stores: col = o (coalesced), row = (reg&3)+8*(reg>>2)+4*(lane>>5) ----
    int wa = w0 + 2 * wv;
    #pragma unroll
    for (int tw = 0; tw < 2; tw++) {
        int w = wa + tw;
        #pragma unroll
        for (int c = 0; c < 2; c++) {
            float* base = dst + ((size_t)b * 65536 + (size_t)(h * 32 + w) * 64 + c * 32) * 32;
            #pragma unroll
            for (int reg = 0; reg < 16; reg++) {
                int row = (reg & 3) + 8 * (reg >> 2) + 4 * (l >> 5);
                base[row * 32 + o] = acc[tw][c][reg];
            }
        }
    }
}

extern "C" void kernel_launch(void* const* d_in, const int* in_sizes, int n_in,
                              void* d_out, int out_size, void* d_ws, size_t ws_size,
                              hipStream_t stream) {
    const float* wu   = (const float*)d_in[1];
    const float* buI  = (const float*)d_in[2];
    const float* wl   = (const float*)d_in[3];
    const float* blI  = (const float*)d_in[4];
    const float* kk   = (const float*)d_in[5];
    const float* bias = (const float*)d_in[6];

    float* out  = (float*)d_out;
    float* outU = out;
    float* buO  = out + 16777216;
    float* outL = out + 16777216 + 256;
    float* blO  = out + 2 * 16777216 + 256;

    uint16_t* ktb = (uint16_t*)d_ws;   // 73728 B

    k_prep<<<146, 256, 0, stream>>>(kk, ktb, buI, blI, buO, blO);
    k_main<<<2048, 256, 0, stream>>>(wu, wl, ktb, bias, outU, outL, buO, blO);
}

// Round 6
// 128.822 us; speedup vs baseline: 1.2922x; 1.2922x over previous
//
#include <hip/hip_runtime.h>
#include <cstdint>

typedef __attribute__((ext_vector_type(8))) short short8;
typedef __attribute__((ext_vector_type(16))) float f32x16;

__device__ inline uint32_t f2bf(float f) {
    union { float f; uint32_t u; } x; x.f = f;
    return (x.u + 0x7FFF + ((x.u >> 16) & 1)) >> 16;
}

// Convert kernel fp32 [9][64][64] -> bf16 ktb (same order), init bias outputs.
__global__ void k_prep(const float* __restrict__ kk, uint16_t* __restrict__ ktb,
                       const float* __restrict__ buI, const float* __restrict__ blI,
                       float* __restrict__ buO, float* __restrict__ blO) {
    int i = blockIdx.x * 256 + threadIdx.x;
    if (i < 36864) ktb[i] = (uint16_t)f2bf(kk[i]);
    else if (i < 36864 + 256) buO[i - 36864] = buI[i - 36864];
    else if (i < 36864 + 512) blO[i - 36864 - 256] = blI[i - 36864 - 256];
}

// Block: (b, UL, h, w-chunk of 8). 4 waves, wave owns 2 w's.
// LDS: ONE kh-row of 10 sites, site = [32 o][64 co] bf16 XOR-swizzled 16B chunks.
// launch_bounds(256,3): 170 unified regs -> 64 AGPR acc + ~106 arch VGPRs, no spill.
__global__ __launch_bounds__(256, 3) void k_main(
    const float* __restrict__ wu, const float* __restrict__ wl,
    const uint16_t* __restrict__ ktb, const float* __restrict__ bias,
    float* __restrict__ outU, float* __restrict__ outL,
    float* __restrict__ buO, float* __restrict__ blO)
{
    __shared__ uint16_t tiles[10][2048];    // 40960 B

    int t  = threadIdx.x;
    int l  = t & 63;
    int wv = t >> 6;
    int o  = l & 31;            // n_out index (frag col, stride-1 in memory)
    int ch = l >> 5;            // co-half selector (compute phase)

    // staging lane geometry: q = o-quad, g = co-pair index
    int q  = l & 7;             // o0 = 4q
    int g  = l >> 3;            // co = 2g + 16p
    int o0 = q * 4;

    // XCD-chunk swizzle: h innermost within an XCD's contiguous chunk
    int bid  = blockIdx.x;
    int virt = (bid & 7) * 256 + (bid >> 3);
    int h    = virt & 31;
    int wc   = (virt >> 5) & 3;
    int UL   = (virt >> 7) & 1;
    int b    = virt >> 8;
    int w0   = wc * 8;

    const float* src = UL ? wl : wu;
    float* dst  = UL ? outL : outU;
    float* bdst = UL ? blO : buO;

    // bias values for this thread's co pairs (hoisted, 8 regs)
    float2 breg[4];
    #pragma unroll
    for (int p = 0; p < 4; p++)
        breg[p] = *(const float2*)(bias + 2 * g + 16 * p);

    float bp[4] = {0.f, 0.f, 0.f, 0.f};    // bias partials for o = o0+0..3

    f32x16 acc[2][2];
    #pragma unroll
    for (int a = 0; a < 2; a++)
        #pragma unroll
        for (int c = 0; c < 2; c++) acc[a][c] = (f32x16)0.f;

    for (int r = 0; r < 3; r++) {
        int hh = h + 1 - r;                 // adjoint: row h reads conv-out row h+1-kh
        if ((unsigned)hh >= 32u) continue;  // block-uniform

        __syncthreads();                    // previous row's readers done

        // ---- stage row r: sites wv, wv+4, wv+8 ----
        for (int s = wv; s < 10; s += 4) {
            int ww = w0 - 1 + s;
            char* lp = (char*)tiles + s * 4096;
            if ((unsigned)ww >= 32u) {
                #pragma unroll
                for (int p = 0; p < 4; p++) {
                    int co    = 2 * g + 16 * p;
                    int chunk = (g >> 2) + 2 * p;
                    int cb    = (co & 7) << 1;
                    #pragma unroll
                    for (int dd = 0; dd < 4; dd++) {
                        int oo = o0 + dd;
                        *(uint32_t*)(lp + oo * 128 + ((chunk ^ (oo & 7)) << 4) + cb) = 0u;
                    }
                }
                continue;
            }
            const float* base = src + ((size_t)b * 65536 + (size_t)(hh * 32 + ww) * 64) * 32;
            // issue all 8 coalesced 16B loads before any use (deep MLP)
            float4 gA[4], gB[4];
            #pragma unroll
            for (int p = 0; p < 4; p++) {
                int co = 2 * g + 16 * p;
                gA[p] = *(const float4*)(base + co * 32 + o0);
                gB[p] = *(const float4*)(base + (co + 1) * 32 + o0);
            }
            bool ctr = (r == 1) && (s >= 1) && (s <= 8);   // center row: each elem once
            #pragma unroll
            for (int p = 0; p < 4; p++) {
                int co    = 2 * g + 16 * p;
                int chunk = (g >> 2) + 2 * p;
                int cb    = (co & 7) << 1;
                if (ctr) {
                    bp[0] = fmaf(gA[p].x, breg[p].x, fmaf(gB[p].x, breg[p].y, bp[0]));
                    bp[1] = fmaf(gA[p].y, breg[p].x, fmaf(gB[p].y, breg[p].y, bp[1]));
                    bp[2] = fmaf(gA[p].z, breg[p].x, fmaf(gB[p].z, breg[p].y, bp[2]));
                    bp[3] = fmaf(gA[p].w, breg[p].x, fmaf(gB[p].w, breg[p].y, bp[3]));
                }
                uint32_t d0 = f2bf(gA[p].x) | (f2bf(gB[p].x) << 16);
                uint32_t d1 = f2bf(gA[p].y) | (f2bf(gB[p].y) << 16);
                uint32_t d2 = f2bf(gA[p].z) | (f2bf(gB[p].z) << 16);
                uint32_t d3 = f2bf(gA[p].w) | (f2bf(gB[p].w) << 16);
                uint32_t dw[4] = {d0, d1, d2, d3};
                #pragma unroll
                for (int dd = 0; dd < 4; dd++) {
                    int oo = o0 + dd;
                    *(uint32_t*)(lp + oo * 128 + ((chunk ^ (oo & 7)) << 4) + cb) = dw[dd];
                }
            }
        }

        __syncthreads();                    // row staged

        // ---- compute row r (kidx outer: only 6 A-frags live) ----
        #pragma unroll
        for (int kidx = 0; kidx < 4; kidx++) {
            short8 A[3][2];
            #pragma unroll
            for (int kw = 0; kw < 3; kw++)
                #pragma unroll
                for (int c = 0; c < 2; c++)
                    A[kw][c] = *(const short8*)&ktb[(((r * 3 + kw) * 64) + c * 32 + (l & 31)) * 64
                                                    + kidx * 16 + ch * 8];
            #pragma unroll
            for (int si = 0; si < 4; si++) {
                int s = 2 * wv + si;
                int chunk = kidx * 2 + ch;
                short8 Bf = *(const short8*)&tiles[s][o * 64 + ((chunk ^ (o & 7)) << 3)];
                #pragma unroll
                for (int tw = 0; tw < 2; tw++) {
                    int kw = tw + 2 - si;              // compile-time under unroll
                    if (kw >= 0 && kw <= 2) {
                        #pragma unroll
                        for (int c = 0; c < 2; c++)
                            acc[tw][c] = __builtin_amdgcn_mfma_f32_32x32x16_bf16(
                                A[kw][c], Bf, acc[tw][c], 0, 0, 0);
                    }
                }
            }
        }
    }

    // ---- bias reduction: shfl pre-reduce (lanes sharing o differ in g bits) ----
    #pragma unroll
    for (int dd = 0; dd < 4; dd++) {
        float v = bp[dd];
        v += __shfl_xor(v, 8);
        v += __shfl_xor(v, 16);
        v += __shfl_xor(v, 32);
        bp[dd] = v;
    }
    __syncthreads();                       // compute done; tiles reusable
    float* bsum = (float*)&tiles[0][0];
    if (t < 32) bsum[t] = 0.f;
    __syncthreads();
    if (g == 0) {                          // lane q of each wave holds wave totals
        #pragma unroll
        for (int dd = 0; dd < 4; dd++) atomicAdd(&bsum[4 * q + dd], bp[dd]);
    }
    __syncthreads();
    if (t < 32) atomicAdd(&bdst[b * 32 + t], bsum[t]);

    // ---- stores: col = o (coalesced), row = (reg&3)+8*(reg>>2)+4*(lane>>5) ----
    int wa = w0 + 2 * wv;
    #pragma unroll
    for (int tw = 0; tw < 2; tw++) {
        int w = wa + tw;
        #pragma unroll
        for (int c = 0; c < 2; c++) {
            float* base = dst + ((size_t)b * 65536 + (size_t)(h * 32 + w) * 64 + c * 32) * 32;
            #pragma unroll
            for (int reg = 0; reg < 16; reg++) {
                int row = (reg & 3) + 8 * (reg >> 2) + 4 * (l >> 5);
                base[row * 32 + o] = acc[tw][c][reg];
            }
        }
    }
}

extern "C" void kernel_launch(void* const* d_in, const int* in_sizes, int n_in,
                              void* d_out, int out_size, void* d_ws, size_t ws_size,
                              hipStream_t stream) {
    const float* wu   = (const float*)d_in[1];
    const float* buI  = (const float*)d_in[2];
    const float* wl   = (const float*)d_in[3];
    const float* blI  = (const float*)d_in[4];
    const float* kk   = (const float*)d_in[5];
    const float* bias = (const float*)d_in[6];

    float* out  = (float*)d_out;
    float* outU = out;
    float* buO  = out + 16777216;
    float* outL = out + 16777216 + 256;
    float* blO  = out + 2 * 16777216 + 256;

    uint16_t* ktb = (uint16_t*)d_ws;   // 73728 B

    k_prep<<<146, 256, 0, stream>>>(kk, ktb, buI, blI, buO, blO);
    k_main<<<2048, 256, 0, stream>>>(wu, wl, ktb, bias, outU, outL, buO, blO);
}